// Round 7
// baseline (162.002 us; speedup 1.0000x reference)
//
#include <hip/hip_runtime.h>

// Problem constants: T=16, H=1280, W=1280, N=64 boxes.
#define TT 16
#define HH 1280
#define WW 1280
#define NBOX 64
#define W4 (WW / 4)             // 320 float4 per row
#define SLICE4 (HH * W4)        // 409600 float4 per T-slice
#define CHUNK 4096              // float4 per block (64 KB, contiguous)
#define NBLK (TT * SLICE4 / CHUNK)   // 1600 blocks; 100 blocks per slice exactly

// K1: build row/col membership bitmasks (one bit per box) in d_ws.
// 2560 work items over 10 blocks -- parallel, ~2 us.
__global__ void build_masks_kernel(const int* __restrict__ boxes,
                                   unsigned long long* __restrict__ rowmask,
                                   unsigned long long* __restrict__ colmask) {
    __shared__ int bx1[NBOX], by1[NBOX], bx2[NBOX], by2[NBOX];
    int tid = threadIdx.x;
    if (tid < NBOX) {
        int4 b = ((const int4*)boxes)[tid];   // (x1, y1, x2, y2)
        bx1[tid] = b.x; by1[tid] = b.y; bx2[tid] = b.z; by2[tid] = b.w;
    }
    __syncthreads();
    int g = blockIdx.x * 256 + tid;           // 0..2559
    if (g < HH) {
        int y = g;
        unsigned long long m = 0ull;
#pragma unroll
        for (int b = 0; b < NBOX; ++b)
            if (by1[b] <= y && y < by2[b]) m |= (1ull << b);
        rowmask[y] = m;
    } else if (g < HH + WW) {
        int x = g - HH;
        unsigned long long m = 0ull;
#pragma unroll
        for (int b = 0; b < NBOX; ++b)
            if (bx1[b] <= x && x < bx2[b]) m |= (1ull << b);
        colmask[x] = m;
    }
}

// K2: per-site weight map, uchar4 per (y,x4) site. 409600 sites, ~2 us.
__global__ void __launch_bounds__(256)
build_wmap_kernel(const unsigned long long* __restrict__ rowmask,
                  const unsigned long long* __restrict__ colmask,
                  uchar4* __restrict__ wmap) {
    int idx = blockIdx.x * 256 + threadIdx.x; // exactly SLICE4 threads
    int y  = idx / W4;
    int x4 = idx - y * W4;
    unsigned long long rm = rowmask[y];
    int x = x4 * 4;
    uchar4 w;
    w.x = (unsigned char)__popcll(rm & colmask[x + 0]);
    w.y = (unsigned char)__popcll(rm & colmask[x + 1]);
    w.z = (unsigned char)__popcll(rm & colmask[x + 2]);
    w.w = (unsigned char)__popcll(rm & colmask[x + 3]);
    wmap[idx] = w;
}

// K3: THE experiment -- perfectly sequential streaming read.
// Block b owns data[b*4096 .. b*4096+4095] (contiguous 64 KB; 100 blocks per
// T-slice, so a block never crosses a slice). Each wave-instruction reads a
// contiguous 1 KB; iterations advance by 4 KB. wmap is read contiguously too
// (256 B per wave-instr, L2/L3-hot after slice 0). This matches the geometry
// of the only access patterns measured at >6 TB/s on this machine (m13 copy,
// poison fill) -- vs the 6.55 MB slice-strided walks that all plateau at
// ~1.6 TB/s effective.
__global__ void __launch_bounds__(256, 4)
stream_sum_kernel(const float4* __restrict__ data,
                  const uchar4* __restrict__ wmap,
                  float* __restrict__ out) {
    const int tid = threadIdx.x;
    const int blk = blockIdx.x;               // 0..1599
    const int t   = blk / 100;                // slice id (SALU magic-div)
    const int sbase = (blk - t * 100) * CHUNK;// site offset within slice

    const float4* p  = data + blk * CHUNK;
    const uchar4* wp = wmap + sbase;

    // Issue all 32 loads back-to-back (16 data dwordx4 + 16 wmap dword).
    float4 v[16];
    uchar4 wb[16];
#pragma unroll
    for (int i = 0; i < 16; ++i) v[i]  = p[i * 256 + tid];
#pragma unroll
    for (int i = 0; i < 16; ++i) wb[i] = wp[i * 256 + tid];

    float a0 = 0.f, a1 = 0.f, a2 = 0.f, a3 = 0.f;
#pragma unroll
    for (int i = 0; i < 16; ++i) {
        a0 += v[i].x * (float)wb[i].x;        // v_cvt_f32_ubyte0..3
        a1 += v[i].y * (float)wb[i].y;
        a2 += v[i].z * (float)wb[i].z;
        a3 += v[i].w * (float)wb[i].w;
    }
    float acc = (a0 + a1) + (a2 + a3);

    // 64-lane wave shuffle reduction -> LDS -> one atomic per block.
#pragma unroll
    for (int off = 32; off > 0; off >>= 1)
        acc += __shfl_down(acc, off, 64);

    __shared__ float wsum[4];
    int lane = tid & 63;
    int wid  = tid >> 6;
    if (lane == 0) wsum[wid] = acc;
    __syncthreads();
    if (tid == 0) {
        float s = (wsum[0] + wsum[1]) + (wsum[2] + wsum[3]);
        atomicAdd(out, s);
    }
}

extern "C" void kernel_launch(void* const* d_in, const int* in_sizes, int n_in,
                              void* d_out, int out_size, void* d_ws, size_t ws_size,
                              hipStream_t stream) {
    const float* data = (const float*)d_in[0];        // (T,H,W) float32
    const int* boxes  = (const int*)d_in[1];          // (N,4) int32
    float* out = (float*)d_out;                       // scalar (poisoned 0xAA)

    // d_ws layout (poison fills happen regardless of use -- R6 profile):
    // rowmask[1280] u64, colmask[1280] u64, wmap[409600] uchar4.
    unsigned long long* rowmask = (unsigned long long*)d_ws;
    unsigned long long* colmask = rowmask + HH;
    uchar4* wmap = (uchar4*)(colmask + WW);

    hipMemsetAsync(out, 0, sizeof(float), stream);
    build_masks_kernel<<<10, 256, 0, stream>>>(boxes, rowmask, colmask);
    build_wmap_kernel<<<SLICE4 / 256, 256, 0, stream>>>(rowmask, colmask, wmap);
    stream_sum_kernel<<<NBLK, 256, 0, stream>>>(
        (const float4*)data, wmap, out);
}

// Round 8
// 160.195 us; speedup vs baseline: 1.0113x; 1.0113x over previous
//
#include <hip/hip_runtime.h>

// Problem constants: T=16, H=1280, W=1280, N=64 boxes.
#define TT 16
#define HH 1280
#define WW 1280
#define NBOX 64
#define W4 (WW / 4)             // 320 float4 per row
#define SLICE4 (HH * W4)        // 409600 float4 per T-slice

// K1: build row/col membership bitmasks (one bit per box) in d_ws.
// PARALLEL: 2560 work items over 10 blocks (~3 us). The old 1-block serial
// version cost ~65 us per replay (R1-R4 totals only reconcile with that).
__global__ void build_masks_kernel(const int* __restrict__ boxes,
                                   unsigned long long* __restrict__ rowmask,
                                   unsigned long long* __restrict__ colmask) {
    __shared__ int bx1[NBOX], by1[NBOX], bx2[NBOX], by2[NBOX];
    int tid = threadIdx.x;
    if (tid < NBOX) {
        int4 b = ((const int4*)boxes)[tid];   // (x1, y1, x2, y2)
        bx1[tid] = b.x; by1[tid] = b.y; bx2[tid] = b.z; by2[tid] = b.w;
    }
    __syncthreads();
    int g = blockIdx.x * 256 + tid;           // 0..2559
    if (g < HH) {
        int y = g;
        unsigned long long m = 0ull;
#pragma unroll
        for (int b = 0; b < NBOX; ++b)
            if (by1[b] <= y && y < by2[b]) m |= (1ull << b);
        rowmask[y] = m;
    } else if (g < HH + WW) {
        int x = g - HH;
        unsigned long long m = 0ull;
#pragma unroll
        for (int b = 0; b < NBOX; ++b)
            if (bx1[b] <= x && x < bx2[b]) m |= (1ull << b);
        colmask[x] = m;
    }
}

// K2: EXACT R2 structure -- the variant whose steady-state time back-computes
// to ~40 us (best of all 7 rounds). One thread per (y,x4) site, all T=16
// slice loads issued back-to-back (v[16], 64 data VGPRs in flight), weights
// from rowmask/colmask popcount (masks are 20 KB, L2-hot). No launch_bounds
// occupancy cap beyond block size -- R2 compiled this without spills.
__global__ void __launch_bounds__(256)
weighted_sum_kernel(const float4* __restrict__ data,
                    const unsigned long long* __restrict__ rowmask,
                    const longlong2* __restrict__ colmask2,
                    float* __restrict__ out) {
    int idx = blockIdx.x * 256 + threadIdx.x;     // exactly SLICE4 threads
    int y  = idx / W4;
    int x4 = idx - y * W4;

    unsigned long long rm = rowmask[y];
    longlong2 c01 = colmask2[x4 * 2 + 0];         // colmask[4*x4 + 0,1]
    longlong2 c23 = colmask2[x4 * 2 + 1];         // colmask[4*x4 + 2,3]
    float w0 = (float)__popcll(rm & (unsigned long long)c01.x);
    float w1 = (float)__popcll(rm & (unsigned long long)c01.y);
    float w2 = (float)__popcll(rm & (unsigned long long)c23.x);
    float w3 = (float)__popcll(rm & (unsigned long long)c23.y);

    const float4* p = data + idx;
    float4 v[TT];
#pragma unroll
    for (int t = 0; t < TT; ++t)
        v[t] = p[t * SLICE4];                     // 16 independent dwordx4

    float a0 = 0.f, a1 = 0.f, a2 = 0.f, a3 = 0.f;
#pragma unroll
    for (int t = 0; t < TT; t += 4) {
        a0 += v[t + 0].x * w0 + v[t + 0].y * w1 + v[t + 0].z * w2 + v[t + 0].w * w3;
        a1 += v[t + 1].x * w0 + v[t + 1].y * w1 + v[t + 1].z * w2 + v[t + 1].w * w3;
        a2 += v[t + 2].x * w0 + v[t + 2].y * w1 + v[t + 2].z * w2 + v[t + 2].w * w3;
        a3 += v[t + 3].x * w0 + v[t + 3].y * w1 + v[t + 3].z * w2 + v[t + 3].w * w3;
    }
    float acc = (a0 + a1) + (a2 + a3);

    // 64-lane wave shuffle reduction -> LDS -> one atomic per block.
#pragma unroll
    for (int off = 32; off > 0; off >>= 1)
        acc += __shfl_down(acc, off, 64);

    __shared__ float wsum[4];
    int lane = threadIdx.x & 63;
    int wid  = threadIdx.x >> 6;
    if (lane == 0) wsum[wid] = acc;
    __syncthreads();
    if (threadIdx.x == 0) {
        float s = (wsum[0] + wsum[1]) + (wsum[2] + wsum[3]);
        atomicAdd(out, s);
    }
}

extern "C" void kernel_launch(void* const* d_in, const int* in_sizes, int n_in,
                              void* d_out, int out_size, void* d_ws, size_t ws_size,
                              hipStream_t stream) {
    const float* data = (const float*)d_in[0];        // (T,H,W) float32
    const int* boxes  = (const int*)d_in[1];          // (N,4) int32
    float* out = (float*)d_out;                       // scalar (poisoned 0xAA)

    // d_ws: rowmask[1280] u64, colmask[1280] u64 (colmask 16B-aligned).
    unsigned long long* rowmask = (unsigned long long*)d_ws;
    unsigned long long* colmask = rowmask + HH;

    hipMemsetAsync(out, 0, sizeof(float), stream);
    build_masks_kernel<<<10, 256, 0, stream>>>(boxes, rowmask, colmask);
    weighted_sum_kernel<<<SLICE4 / 256, 256, 0, stream>>>(
        (const float4*)data, rowmask, (const longlong2*)colmask, out);
}

// Round 9
// 159.464 us; speedup vs baseline: 1.0159x; 1.0046x over previous
//
#include <hip/hip_runtime.h>

// Problem constants: T=16, H=1280, W=1280, N=64 boxes.
#define TT 16
#define HH 1280
#define WW 1280
#define NBOX 64
#define W4 (WW / 4)             // 320 float4 per row
#define SLICE4 (HH * W4)        // 409600 float4 per T-slice

// K1: build row/col membership bitmasks (one bit per box) in d_ws.
// Parallel: 2560 work items over 10 blocks (~3 us).
__global__ void build_masks_kernel(const int* __restrict__ boxes,
                                   unsigned long long* __restrict__ rowmask,
                                   unsigned long long* __restrict__ colmask) {
    __shared__ int bx1[NBOX], by1[NBOX], bx2[NBOX], by2[NBOX];
    int tid = threadIdx.x;
    if (tid < NBOX) {
        int4 b = ((const int4*)boxes)[tid];   // (x1, y1, x2, y2)
        bx1[tid] = b.x; by1[tid] = b.y; bx2[tid] = b.z; by2[tid] = b.w;
    }
    __syncthreads();
    int g = blockIdx.x * 256 + tid;           // 0..2559
    if (g < HH) {
        int y = g;
        unsigned long long m = 0ull;
#pragma unroll
        for (int b = 0; b < NBOX; ++b)
            if (by1[b] <= y && y < by2[b]) m |= (1ull << b);
        rowmask[y] = m;
    } else if (g < HH + WW) {
        int x = g - HH;
        unsigned long long m = 0ull;
#pragma unroll
        for (int b = 0; b < NBOX; ++b)
            if (bx1[b] <= x && x < bx2[b]) m |= (1ull << b);
        colmask[x] = m;
    }
}

// K2: R8 structure + FORCED memory-level parallelism.
// Evidence (R1: VGPR=16, R5: VGPR=32): the LLVM scheduler sinks loads toward
// uses and inserts early s_waitcnt, collapsing the intended 16-deep load
// batch into 2-4 outstanding loads -> ~900cyc-latency-bound plateau at
// ~1.8 TB/s. sched_barrier(0) after the load block forbids motion across it:
// first FMA waits at vmcnt(15) with 15 loads in flight, and v[16] (64 VGPRs)
// must stay live. No min-waves launch bound -- let VGPR land ~100 (still
// 5 waves/SIMD, 20 waves/CU > the 6.25 blocks/CU the grid needs).
__global__ void __launch_bounds__(256)
weighted_sum_kernel(const float4* __restrict__ data,
                    const unsigned long long* __restrict__ rowmask,
                    const longlong2* __restrict__ colmask2,
                    float* __restrict__ out) {
    int idx = blockIdx.x * 256 + threadIdx.x;     // exactly SLICE4 threads
    int y  = idx / W4;
    int x4 = idx - y * W4;

    // Mask loads issued first; their latency overlaps the data-load batch.
    unsigned long long rm = rowmask[y];
    longlong2 c01 = colmask2[x4 * 2 + 0];         // colmask[4*x4 + 0,1]
    longlong2 c23 = colmask2[x4 * 2 + 1];         // colmask[4*x4 + 2,3]

    const float4* p = data + idx;
    float4 v[TT];
#pragma unroll
    for (int t = 0; t < TT; ++t)
        v[t] = p[t * SLICE4];                     // 16 independent dwordx4

    // Hard scheduling fence: nothing moves across. All 16 loads are
    // outstanding when the first consumer below is scheduled.
    __builtin_amdgcn_sched_barrier(0);

    float w0 = (float)__popcll(rm & (unsigned long long)c01.x);
    float w1 = (float)__popcll(rm & (unsigned long long)c01.y);
    float w2 = (float)__popcll(rm & (unsigned long long)c23.x);
    float w3 = (float)__popcll(rm & (unsigned long long)c23.y);

    float a0 = 0.f, a1 = 0.f, a2 = 0.f, a3 = 0.f;
#pragma unroll
    for (int t = 0; t < TT; t += 4) {
        a0 += v[t + 0].x * w0 + v[t + 0].y * w1 + v[t + 0].z * w2 + v[t + 0].w * w3;
        a1 += v[t + 1].x * w0 + v[t + 1].y * w1 + v[t + 1].z * w2 + v[t + 1].w * w3;
        a2 += v[t + 2].x * w0 + v[t + 2].y * w1 + v[t + 2].z * w2 + v[t + 2].w * w3;
        a3 += v[t + 3].x * w0 + v[t + 3].y * w1 + v[t + 3].z * w2 + v[t + 3].w * w3;
    }
    float acc = (a0 + a1) + (a2 + a3);

    // 64-lane wave shuffle reduction -> LDS -> one atomic per block.
#pragma unroll
    for (int off = 32; off > 0; off >>= 1)
        acc += __shfl_down(acc, off, 64);

    __shared__ float wsum[4];
    int lane = threadIdx.x & 63;
    int wid  = threadIdx.x >> 6;
    if (lane == 0) wsum[wid] = acc;
    __syncthreads();
    if (threadIdx.x == 0) {
        float s = (wsum[0] + wsum[1]) + (wsum[2] + wsum[3]);
        atomicAdd(out, s);
    }
}

extern "C" void kernel_launch(void* const* d_in, const int* in_sizes, int n_in,
                              void* d_out, int out_size, void* d_ws, size_t ws_size,
                              hipStream_t stream) {
    const float* data = (const float*)d_in[0];        // (T,H,W) float32
    const int* boxes  = (const int*)d_in[1];          // (N,4) int32
    float* out = (float*)d_out;                       // scalar (poisoned 0xAA)

    // d_ws: rowmask[1280] u64, colmask[1280] u64 (colmask 16B-aligned).
    unsigned long long* rowmask = (unsigned long long*)d_ws;
    unsigned long long* colmask = rowmask + HH;

    hipMemsetAsync(out, 0, sizeof(float), stream);
    build_masks_kernel<<<10, 256, 0, stream>>>(boxes, rowmask, colmask);
    weighted_sum_kernel<<<SLICE4 / 256, 256, 0, stream>>>(
        (const float4*)data, rowmask, (const longlong2*)colmask, out);
}